// Round 5
// baseline (385.088 us; speedup 1.0000x reference)
//
#include <hip/hip_runtime.h>

#define NSER 8192
#define NTS  400
#define NO   9

__device__ __forceinline__ float frcp(float x){ return __builtin_amdgcn_rcpf(x); }
__device__ __forceinline__ float frsq(float x){ return __builtin_amdgcn_rsqf(x); }
__device__ __forceinline__ float fexp2(float x){ return __builtin_amdgcn_exp2f(x); }   // 2^x
__device__ __forceinline__ float flog2(float x){ return __builtin_amdgcn_logf(x); }    // log2(x)

__global__ void zero_kernel(float* out, int n){
    int i = blockIdx.x*blockDim.x + threadIdx.x;
    if (i < n) out[i] = 0.f;
}

// One thread = one series.
// Round-5: y enters only via 5 Gram scalars (Y2, G, Gc0..2), computed one step
// ahead (state-independent stall filler). rsqrt replaces log2-based det^-1/2.
// P1 consumed in adjugate form scaled by pt1*idet.
__global__ __launch_bounds__(64, 1)
void rskf_kernel(const float* __restrict__ y,   // (N, NT, O)
                 const float* __restrict__ B1,  // 3x3
                 const float* __restrict__ B2,  // 1
                 const float* __restrict__ l1,  // 6
                 const float* __restrict__ l2,  // 8
                 const float* __restrict__ lq,  // 4
                 const float* __restrict__ lr,  // 9
                 const float* __restrict__ g0p, // 1
                 const float* __restrict__ gc,  // 3
                 float* __restrict__ out)
{
    const int n = blockIdx.x*64 + (int)threadIdx.x;

    const float L2E = 1.4426950408889634f;   // log2(e)
    const float LN2 = 0.6931471805599453f;
    const float K2  = 0.5f*L2E;
    const float LOG2PI = 1.8378770664093453f; // ln(2*pi)

    // ---- uniform parameter prep ----
    float Bm[3][3];
    #pragma unroll
    for (int i=0;i<3;++i)
        #pragma unroll
        for (int j=0;j<3;++j) Bm[i][j] = B1[i*3+j];
    const float b2 = B2[0];
    const float b2sq = b2*b2;
    float Bb[3][3];
    #pragma unroll
    for (int i=0;i<3;++i)
        #pragma unroll
        for (int j=0;j<3;++j) Bb[i][j] = b2*Bm[i][j];
    float qd[4];
    #pragma unroll
    for (int i=0;i<4;++i) qd[i] = fexp2(lq[i]*L2E);

    float c[9];
    c[0]=1.f; c[1]=l1[0]; c[2]=l1[1];
    c[3]=1.f; c[4]=l1[2]; c[5]=l1[3];
    c[6]=1.f; c[7]=l1[4]; c[8]=l1[5];
    float mv[9]; mv[0]=1.f;
    #pragma unroll
    for (int o=1;o<9;++o) mv[o]=l2[o-1];

    float invD[9];
    float logdetD2 = 0.f;
    #pragma unroll
    for (int o=0;o<9;++o){
        float D  = fexp2(lr[o]*L2E) + 1e-6f;   // R diag + jitter
        logdetD2 += flog2(D);
        invD[o]  = 1.f/D;
    }
    const float s0 = invD[0] + c[1]*c[1]*invD[1] + c[2]*c[2]*invD[2];
    const float s1 = invD[3] + c[4]*c[4]*invD[4] + c[5]*c[5]*invD[5];
    const float s2 = invD[6] + c[7]*c[7]*invD[7] + c[8]*c[8]*invD[8];
    float smm = 0.f;
    #pragma unroll
    for (int o=0;o<9;++o) smm += mv[o]*mv[o]*invD[o];
    const float invs0=1.f/s0, invs1=1.f/s1, invs2=1.f/s2;
    const float k00=invs0*invs0, k01=invs0*invs1, k02=invs0*invs2;
    const float k11=invs1*invs1, k12=invs1*invs2, k22=invs2*invs2;
    const float C2f2 = 0.5f*(9.f*LOG2PI*L2E + logdetD2);
    const float C1f2 = C2f2 + 0.5f*(flog2(s0)+flog2(s1)+flog2(s2));
    const float g0L  = g0p[0]*L2E;
    const float gcL0 = gc[0]*L2E, gcL1 = gc[1]*L2E, gcL2 = gc[2]*L2E;

    // ---- state (P as 10-scalar symmetric) ----
    float prob1=0.99f, prob2=0.01f;
    float eta0=0.f, eta1v=0.f, eta2v=0.f, eta3=0.f;
    float P00=1000.f,P01=0.f,P02=0.f,P03=0.f,P11=1000.f,P12=0.f,P13=0.f,
          P22=1000.f,P23=0.f,P33=1000.f;

    const float* __restrict__ yp = y + (size_t)n*(NTS*NO);

    // pre-loop: gram for t=0, prefetch y[1]
    float gY2, gG, gGc0, gGc1, gGc2;
    {
        float y0[9];
        #pragma unroll
        for (int o=0;o<9;++o) y0[o]=yp[o];
        float zi[9];
        #pragma unroll
        for (int o=0;o<9;++o) zi[o]=invD[o]*y0[o];
        float e01=fmaf(zi[1],y0[1], zi[0]*y0[0]);
        float e23=fmaf(zi[3],y0[3], zi[2]*y0[2]);
        float e45=fmaf(zi[5],y0[5], zi[4]*y0[4]);
        float e67=fmaf(zi[7],y0[7], zi[6]*y0[6]);
        gY2 = (e01+e23)+(e45+e67)+zi[8]*y0[8];
        float ga=fmaf(mv[1],zi[1], zi[0]);
        float gb=fmaf(mv[3],zi[3], mv[2]*zi[2]);
        float gcc=fmaf(mv[5],zi[5], mv[4]*zi[4]);
        float gd=fmaf(mv[7],zi[7], mv[6]*zi[6]);
        gG = (ga+gb)+(gcc+gd)+mv[8]*zi[8];
        gGc0 = fmaf(c[2],zi[2], fmaf(c[1],zi[1], zi[0]));
        gGc1 = fmaf(c[5],zi[5], fmaf(c[4],zi[4], zi[3]));
        gGc2 = fmaf(c[8],zi[8], fmaf(c[7],zi[7], zi[6]));
    }
    float ynx[9];
    #pragma unroll
    for (int o=0;o<9;++o) ynx[o]=yp[NO+o];

    float acc2=0.f;   // -log2(marg) accumulator

    #pragma unroll 2
    for (int t=0;t<NTS;++t){
        // ---- state-independent: gram for t+1 from ynx; load y[t+2] ----
        float nY2,nG,nGc0,nGc1,nGc2;
        {
            float zi[9];
            #pragma unroll
            for (int o=0;o<9;++o) zi[o]=invD[o]*ynx[o];
            float e01=fmaf(zi[1],ynx[1], zi[0]*ynx[0]);
            float e23=fmaf(zi[3],ynx[3], zi[2]*ynx[2]);
            float e45=fmaf(zi[5],ynx[5], zi[4]*ynx[4]);
            float e67=fmaf(zi[7],ynx[7], zi[6]*ynx[6]);
            nY2 = (e01+e23)+(e45+e67)+zi[8]*ynx[8];
            float ga=fmaf(mv[1],zi[1], zi[0]);
            float gb=fmaf(mv[3],zi[3], mv[2]*zi[2]);
            float gcc=fmaf(mv[5],zi[5], mv[4]*zi[4]);
            float gd=fmaf(mv[7],zi[7], mv[6]*zi[6]);
            nG = (ga+gb)+(gcc+gd)+mv[8]*zi[8];
            nGc0 = fmaf(c[2],zi[2], fmaf(c[1],zi[1], zi[0]));
            nGc1 = fmaf(c[5],zi[5], fmaf(c[4],zi[4], zi[3]));
            nGc2 = fmaf(c[8],zi[8], fmaf(c[7],zi[7], zi[6]));
        }
        const int tn2 = (t+2<NTS)?(t+2):(NTS-1);
        const float* yp2 = yp + tn2*NO;
        float ynew[9];
        #pragma unroll
        for (int o=0;o<9;++o) ynew[o]=yp2[o];

        // ---- transition prob (from eta(t-1), early) ----
        float lg = fmaf(gcL2, eta2v, fmaf(gcL1, eta1v, fmaf(gcL0, eta0, g0L)));
        float p11 = frcp(1.f + fexp2(-lg));
        float pm  = prob1*p11;
        float w2f = (prob1 - pm) + prob2;

        // ---- mean prediction ----
        float ep0 = fmaf(Bm[0][2],eta2v, fmaf(Bm[0][1],eta1v, Bm[0][0]*eta0));
        float ep1 = fmaf(Bm[1][2],eta2v, fmaf(Bm[1][1],eta1v, Bm[1][0]*eta0));
        float ep2 = fmaf(Bm[2][2],eta2v, fmaf(Bm[2][1],eta1v, Bm[2][0]*eta0));
        float ep3 = b2*eta3;

        // ---- covariance prediction (symmetric storage) ----
        float U00 = fmaf(Bm[0][2],P02, fmaf(Bm[0][1],P01, Bm[0][0]*P00));
        float U01 = fmaf(Bm[0][2],P12, fmaf(Bm[0][1],P11, Bm[0][0]*P01));
        float U02 = fmaf(Bm[0][2],P22, fmaf(Bm[0][1],P12, Bm[0][0]*P02));
        float U10 = fmaf(Bm[1][2],P02, fmaf(Bm[1][1],P01, Bm[1][0]*P00));
        float U11 = fmaf(Bm[1][2],P12, fmaf(Bm[1][1],P11, Bm[1][0]*P01));
        float U12 = fmaf(Bm[1][2],P22, fmaf(Bm[1][1],P12, Bm[1][0]*P02));
        float U20 = fmaf(Bm[2][2],P02, fmaf(Bm[2][1],P01, Bm[2][0]*P00));
        float U21 = fmaf(Bm[2][2],P12, fmaf(Bm[2][1],P11, Bm[2][0]*P01));
        float U22 = fmaf(Bm[2][2],P22, fmaf(Bm[2][1],P12, Bm[2][0]*P02));
        float Pp00 = fmaf(U02,Bm[0][2], fmaf(U01,Bm[0][1], U00*Bm[0][0])) + qd[0];
        float Pp01 = fmaf(U02,Bm[1][2], fmaf(U01,Bm[1][1], U00*Bm[1][0]));
        float Pp02 = fmaf(U02,Bm[2][2], fmaf(U01,Bm[2][1], U00*Bm[2][0]));
        float Pp11 = fmaf(U12,Bm[1][2], fmaf(U11,Bm[1][1], U10*Bm[1][0])) + qd[1];
        float Pp12 = fmaf(U12,Bm[2][2], fmaf(U11,Bm[2][1], U10*Bm[2][0]));
        float Pp22 = fmaf(U22,Bm[2][2], fmaf(U21,Bm[2][1], U20*Bm[2][0])) + qd[2];
        float pb0 = fmaf(Bb[0][2],P23, fmaf(Bb[0][1],P13, Bb[0][0]*P03));
        float pb1 = fmaf(Bb[1][2],P23, fmaf(Bb[1][1],P13, Bb[1][0]*P03));
        float pb2 = fmaf(Bb[2][2],P23, fmaf(Bb[2][1],P13, Bb[2][0]*P03));
        float Pp33 = fmaf(b2sq, P33, qd[3]);

        // ================= regime 1 (Woodbury via Gram scalars) ================
        float u0 = fmaf(-ep0, s0, gGc0);
        float u1 = fmaf(-ep1, s1, gGc1);
        float u2 = fmaf(-ep2, s2, gGc2);
        float t0 = gY2 - (fmaf(ep2, gGc2+u2, fmaf(ep1, gGc1+u1, ep0*(gGc0+u0))));
        float a00=Pp00+invs0, a01=Pp01, a02=Pp02;
        float a11=Pp11+invs1, a12=Pp12, a22=Pp22+invs2;
        float i00 = fmaf(a11,a22, -a12*a12);
        float i01 = fmaf(a02,a12, -a01*a22);
        float i02 = fmaf(a01,a12, -a02*a11);
        float det = fmaf(a00,i00, fmaf(a01,i01, a02*i02));
        float i11 = fmaf(a00,a22, -a02*a02);
        float i12 = fmaf(a01,a02, -a00*a12);
        float i22 = fmaf(a00,a11, -a01*a01);
        float idet = frcp(det);
        float rs1  = frsq(det);
        float ub0=u0*invs0, ub1=u1*invs1, ub2=u2*invs2;
        float aw0 = fmaf(i02,ub2, fmaf(i01,ub1, i00*ub0));
        float aw1 = fmaf(i12,ub2, fmaf(i11,ub1, i01*ub0));
        float aw2 = fmaf(i22,ub2, fmaf(i12,ub1, i02*ub0));
        float sWu = fmaf(ub2,aw2, fmaf(ub1,aw1, ub0*aw0));
        float q1  = fmaf(sWu, idet, t0 - fmaf(u2,ub2, fmaf(u1,ub1, u0*ub0)));
        float lik1 = fexp2(fmaf(-K2, q1, -C1f2)) * rs1;
        float w0=aw0*idet, w1=aw1*idet, w2=aw2*idet;
        float e1_0 = fmaf(-invs0, w0, ep0+ub0);
        float e1_1 = fmaf(-invs1, w1, ep1+ub1);
        float e1_2 = fmaf(-invs2, w2, ep2+ub2);
        float e1_3 = ep3 + fmaf(pb2,w2, fmaf(pb1,w1, pb0*w0));
        float ah0 = fmaf(i02,pb2, fmaf(i01,pb1, i00*pb0));
        float ah1 = fmaf(i12,pb2, fmaf(i11,pb1, i01*pb0));
        float ah2 = fmaf(i22,pb2, fmaf(i12,pb1, i02*pb0));
        float pbh = fmaf(pb2,ah2, fmaf(pb1,ah1, pb0*ah0));  // (pb . adj pb)

        // ================= regime 2 (Sherman-Morrison via Gram) ================
        float beta = Pp33;
        float uu  = fmaf(-ep3, smm, gG);
        float t02 = gY2 - ep3*(gG+uu);
        float denom = fmaf(beta, smm, 1.f);
        float iden  = frcp(denom);
        float rs2   = frsq(denom);
        float g2v = uu*iden;
        float q2  = fmaf(-beta*uu, g2v, t02);
        float lik2 = fexp2(fmaf(-K2, q2, -C2f2)) * rs2;
        float e2_0=fmaf(pb0,g2v,ep0), e2_1=fmaf(pb1,g2v,ep1);
        float e2_2=fmaf(pb2,g2v,ep2), e2_3=fmaf(Pp33,g2v,ep3);
        float k2s = smm*iden;

        // ================= IMM mixing =========================================
        float num1 = lik1*pm;
        float num2 = lik2*w2f;
        float marg = num1+num2+1e-9f;
        acc2 -= flog2(marg);
        float imarg = frcp(marg);
        float pt1 = num1*imarg, pt2 = num2*imarg;
        float sig = pt1+pt2;
        float ptid = pt1*idet;
        float c3  = (pt1*pt2)*sig;
        float D0=e1_0-e2_0, D1=e1_1-e2_1, D2=e1_2-e2_2, D3=e1_3-e2_3;
        float cd0=c3*D0, cd1=c3*D1, cd2=c3*D2, cd3=c3*D3;
        float et0 = fmaf(pt1, D0, sig*e2_0);
        float et1 = fmaf(pt1, D1, sig*e2_1);
        float et2 = fmaf(pt1, D2, sig*e2_2);
        float et3 = fmaf(pt1, D3, sig*e2_3);
        float kap = pt2*k2s;
        float p3a0=kap*pb0, p3a1=kap*pb1, p3a2=kap*pb2, p3a3=kap*Pp33;

        // P = pt1*P1 + pt2*Pp - kap*pcol pcol^T + c3*D D^T (P1 in adj form)
        float v;
        v = fmaf(pt1, invs0, pt2*Pp00); v = fmaf(-(k00*i00), ptid, v);
        v = fmaf(-p3a0, pb0, v);        P00 = fmaf(cd0, D0, v);
        v = pt2*Pp01;                   v = fmaf(-(k01*i01), ptid, v);
        v = fmaf(-p3a0, pb1, v);        P01 = fmaf(cd0, D1, v);
        v = pt2*Pp02;                   v = fmaf(-(k02*i02), ptid, v);
        v = fmaf(-p3a0, pb2, v);        P02 = fmaf(cd0, D2, v);
        v = pt2*pb0;                    v = fmaf(invs0*ah0, ptid, v);
        v = fmaf(-p3a0, Pp33, v);       P03 = fmaf(cd0, D3, v);
        v = fmaf(pt1, invs1, pt2*Pp11); v = fmaf(-(k11*i11), ptid, v);
        v = fmaf(-p3a1, pb1, v);        P11 = fmaf(cd1, D1, v);
        v = pt2*Pp12;                   v = fmaf(-(k12*i12), ptid, v);
        v = fmaf(-p3a1, pb2, v);        P12 = fmaf(cd1, D2, v);
        v = pt2*pb1;                    v = fmaf(invs1*ah1, ptid, v);
        v = fmaf(-p3a1, Pp33, v);       P13 = fmaf(cd1, D3, v);
        v = fmaf(pt1, invs2, pt2*Pp22); v = fmaf(-(k22*i22), ptid, v);
        v = fmaf(-p3a2, pb2, v);        P22 = fmaf(cd2, D2, v);
        v = pt2*pb2;                    v = fmaf(invs2*ah2, ptid, v);
        v = fmaf(-p3a2, Pp33, v);       P23 = fmaf(cd2, D3, v);
        v = sig*Pp33;                   v = fmaf(-pbh, ptid, v);
        v = fmaf(-p3a3, Pp33, v);       P33 = fmaf(cd3, D3, v);

        prob1=pt1; prob2=pt2;
        eta0=et0; eta1v=et1; eta2v=et2; eta3=et3;
        gY2=nY2; gG=nG; gGc0=nGc0; gGc1=nGc1; gGc2=nGc2;
        #pragma unroll
        for (int o=0;o<9;++o) ynx[o]=ynew[o];
    }

    float acc = acc2 * LN2;
    #pragma unroll
    for (int off=32; off>0; off>>=1) acc += __shfl_down(acc, off);
    if (threadIdx.x==0) atomicAdd(out, acc);
}

extern "C" void kernel_launch(void* const* d_in, const int* in_sizes, int n_in,
                              void* d_out, int out_size, void* d_ws, size_t ws_size,
                              hipStream_t stream) {
    (void)in_sizes; (void)n_in; (void)d_ws; (void)ws_size;
    float* out = (float*)d_out;
    zero_kernel<<<1, 64, 0, stream>>>(out, out_size);
    rskf_kernel<<<NSER/64, 64, 0, stream>>>(
        (const float*)d_in[0], (const float*)d_in[1], (const float*)d_in[2],
        (const float*)d_in[3], (const float*)d_in[4], (const float*)d_in[5],
        (const float*)d_in[6], (const float*)d_in[7], (const float*)d_in[8],
        out);
}

// Round 6
// 355.741 us; speedup vs baseline: 1.0825x; 1.0825x over previous
//
#include <hip/hip_runtime.h>

#define NSER 8192
#define NTS  400
#define NO   9

typedef float f2 __attribute__((ext_vector_type(2)));

__device__ __forceinline__ float frcp(float x){ return __builtin_amdgcn_rcpf(x); }
__device__ __forceinline__ float frsq(float x){ return __builtin_amdgcn_rsqf(x); }
__device__ __forceinline__ float fexp2(float x){ return __builtin_amdgcn_exp2f(x); }   // 2^x
__device__ __forceinline__ float flog2(float x){ return __builtin_amdgcn_logf(x); }    // log2(x)
__device__ __forceinline__ f2 sp2(float s){ f2 r; r.x=s; r.y=s; return r; }
__device__ __forceinline__ f2 mk2(float a, float b){ f2 r; r.x=a; r.y=b; return r; }

__global__ void zero_kernel(float* out, int n){
    int i = blockIdx.x*blockDim.x + threadIdx.x;
    if (i < n) out[i] = 0.f;
}

// One thread = one series. Round-6:
//  - round-4 algebra (closed-form P1, Delta mixing) -- verified absmax 0.0
//  - P as 10 scalars (no mirrored array writes)
//  - rsqrt(det) likelihood (removes log2->exp2 serial chain)
//  - regime-1/regime-2 pipelines packed as float2 -> v_pk_fma_f32 (2 fp32/inst)
__global__ __launch_bounds__(64, 1)
void rskf_kernel(const float* __restrict__ y,   // (N, NT, O)
                 const float* __restrict__ B1,  // 3x3
                 const float* __restrict__ B2,  // 1
                 const float* __restrict__ l1,  // 6
                 const float* __restrict__ l2,  // 8
                 const float* __restrict__ lq,  // 4
                 const float* __restrict__ lr,  // 9
                 const float* __restrict__ g0p, // 1
                 const float* __restrict__ gc,  // 3
                 float* __restrict__ out)
{
    const int n = blockIdx.x*64 + (int)threadIdx.x;

    const float L2E = 1.4426950408889634f;   // log2(e)
    const float LN2 = 0.6931471805599453f;
    const float K2  = 0.5f*L2E;
    const float LOG2PI = 1.8378770664093453f; // ln(2*pi)

    // ---- uniform parameter prep ----
    float Bm[3][3];
    #pragma unroll
    for (int i=0;i<3;++i)
        #pragma unroll
        for (int j=0;j<3;++j) Bm[i][j] = B1[i*3+j];
    const float b2 = B2[0];
    const float b2sq = b2*b2;
    float Bb[3][3];
    #pragma unroll
    for (int i=0;i<3;++i)
        #pragma unroll
        for (int j=0;j<3;++j) Bb[i][j] = b2*Bm[i][j];
    float qd[4];
    #pragma unroll
    for (int i=0;i<4;++i) qd[i] = fexp2(lq[i]*L2E);

    float c[9];
    c[0]=1.f; c[1]=l1[0]; c[2]=l1[1];
    c[3]=1.f; c[4]=l1[2]; c[5]=l1[3];
    c[6]=1.f; c[7]=l1[4]; c[8]=l1[5];
    float mv[9]; mv[0]=1.f;
    #pragma unroll
    for (int o=1;o<9;++o) mv[o]=l2[o-1];

    float invD[9];
    float logdetD2 = 0.f;
    #pragma unroll
    for (int o=0;o<9;++o){
        float D  = fexp2(lr[o]*L2E) + 1e-6f;   // R diag + jitter
        logdetD2 += flog2(D);
        invD[o]  = 1.f/D;
    }
    // packed coefficient tables: {regime1, regime2}
    f2 c2[9], iD2[9];
    #pragma unroll
    for (int o=0;o<9;++o){ c2[o] = mk2(c[o], mv[o]); iD2[o] = sp2(invD[o]); }

    const float s0 = invD[0] + c[1]*c[1]*invD[1] + c[2]*c[2]*invD[2];
    const float s1 = invD[3] + c[4]*c[4]*invD[4] + c[5]*c[5]*invD[5];
    const float s2 = invD[6] + c[7]*c[7]*invD[7] + c[8]*c[8]*invD[8];
    float smm = 0.f;
    #pragma unroll
    for (int o=0;o<9;++o) smm += mv[o]*mv[o]*invD[o];
    const float invs0=1.f/s0, invs1=1.f/s1, invs2=1.f/s2;
    const float k00=invs0*invs0, k01=invs0*invs1, k02=invs0*invs2;
    const float k11=invs1*invs1, k12=invs1*invs2, k22=invs2*invs2;
    const float C2f2 = 0.5f*(9.f*LOG2PI*L2E + logdetD2);
    const float C1f2 = C2f2 + 0.5f*(flog2(s0)+flog2(s1)+flog2(s2));
    const float g0L  = g0p[0]*L2E;
    const float gcL0 = gc[0]*L2E, gcL1 = gc[1]*L2E, gcL2 = gc[2]*L2E;

    // ---- state ----
    float prob1=0.99f, prob2=0.01f;
    float eta0=0.f, eta1v=0.f, eta2v=0.f, eta3=0.f;
    float P00=1000.f,P01=0.f,P02=0.f,P03=0.f,P11=1000.f,P12=0.f,P13=0.f,
          P22=1000.f,P23=0.f,P33=1000.f;

    const float* __restrict__ yp = y + (size_t)n*(NTS*NO);
    float ynx[9];
    #pragma unroll
    for (int o=0;o<9;++o) ynx[o]=yp[o];
    float acc2=0.f;   // -log2(marg)

    #pragma unroll 2
    for (int t=0;t<NTS;++t){
        // consume prefetched y_t, prefetch y_{t+1}
        float yc[9];
        #pragma unroll
        for (int o=0;o<9;++o) yc[o]=ynx[o];
        const int tn = (t+1<NTS)?(t+1):t;
        const float* ypn = yp + tn*NO;
        #pragma unroll
        for (int o=0;o<9;++o) ynx[o]=ypn[o];

        // transition prob
        float lg = fmaf(gcL2, eta2v, fmaf(gcL1, eta1v, fmaf(gcL0, eta0, g0L)));
        float p11 = frcp(1.f + fexp2(-lg));
        float pm  = prob1*p11;
        float w2f = (prob1 - pm) + prob2;

        // mean prediction
        float ep0 = fmaf(Bm[0][2],eta2v, fmaf(Bm[0][1],eta1v, Bm[0][0]*eta0));
        float ep1 = fmaf(Bm[1][2],eta2v, fmaf(Bm[1][1],eta1v, Bm[1][0]*eta0));
        float ep2 = fmaf(Bm[2][2],eta2v, fmaf(Bm[2][1],eta1v, Bm[2][0]*eta0));
        float ep3 = b2*eta3;

        // covariance prediction (scalar symmetric storage)
        float U00 = fmaf(Bm[0][2],P02, fmaf(Bm[0][1],P01, Bm[0][0]*P00));
        float U01 = fmaf(Bm[0][2],P12, fmaf(Bm[0][1],P11, Bm[0][0]*P01));
        float U02 = fmaf(Bm[0][2],P22, fmaf(Bm[0][1],P12, Bm[0][0]*P02));
        float U10 = fmaf(Bm[1][2],P02, fmaf(Bm[1][1],P01, Bm[1][0]*P00));
        float U11 = fmaf(Bm[1][2],P12, fmaf(Bm[1][1],P11, Bm[1][0]*P01));
        float U12 = fmaf(Bm[1][2],P22, fmaf(Bm[1][1],P12, Bm[1][0]*P02));
        float U20 = fmaf(Bm[2][2],P02, fmaf(Bm[2][1],P01, Bm[2][0]*P00));
        float U21 = fmaf(Bm[2][2],P12, fmaf(Bm[2][1],P11, Bm[2][0]*P01));
        float U22 = fmaf(Bm[2][2],P22, fmaf(Bm[2][1],P12, Bm[2][0]*P02));
        float Pp00 = fmaf(U02,Bm[0][2], fmaf(U01,Bm[0][1], U00*Bm[0][0])) + qd[0];
        float Pp01 = fmaf(U02,Bm[1][2], fmaf(U01,Bm[1][1], U00*Bm[1][0]));
        float Pp02 = fmaf(U02,Bm[2][2], fmaf(U01,Bm[2][1], U00*Bm[2][0]));
        float Pp11 = fmaf(U12,Bm[1][2], fmaf(U11,Bm[1][1], U10*Bm[1][0])) + qd[1];
        float Pp12 = fmaf(U12,Bm[2][2], fmaf(U11,Bm[2][1], U10*Bm[2][0]));
        float Pp22 = fmaf(U22,Bm[2][2], fmaf(U21,Bm[2][1], U20*Bm[2][0])) + qd[2];
        float pb0 = fmaf(Bb[0][2],P23, fmaf(Bb[0][1],P13, Bb[0][0]*P03));
        float pb1 = fmaf(Bb[1][2],P23, fmaf(Bb[1][1],P13, Bb[1][0]*P03));
        float pb2 = fmaf(Bb[2][2],P23, fmaf(Bb[2][1],P13, Bb[2][0]*P03));
        float Pp33 = fmaf(b2sq, P33, qd[3]);

        // ===== packed residual pipeline: x = regime1, y = regime2 =====
        f2 epP0 = mk2(ep0, ep3), epP1 = mk2(ep1, ep3), epP2 = mk2(ep2, ep3);
        f2 r[9], z[9];
        #pragma unroll
        for (int o=0;o<9;++o){
            f2 yv = sp2(yc[o]);
            f2 ep = (o<3)?epP0 : (o<6)?epP1 : epP2;
            r[o] = yv - c2[o]*ep;          // {v1[o], v2[o]}
            z[o] = iD2[o]*r[o];            // {z1[o], z2[o]}
        }
        // quadratic forms {t0, t02}
        f2 ta = z[1]*r[1] + z[0]*r[0];
        f2 tb = z[3]*r[3] + z[2]*r[2];
        f2 tc = z[5]*r[5] + z[4]*r[4];
        f2 td = z[7]*r[7] + z[6]*r[6];
        f2 tt = (ta+tb) + (tc+td) + z[8]*r[8];
        float t0 = tt.x, t02 = tt.y;
        // weighted sums: {u_g, uu_part_g}
        f2 gA = c2[2]*z[2] + (c2[1]*z[1] + c2[0]*z[0]);
        f2 gB = c2[5]*z[5] + (c2[4]*z[4] + c2[3]*z[3]);
        f2 gC = c2[8]*z[8] + (c2[7]*z[7] + c2[6]*z[6]);
        float u0 = gA.x, u1 = gB.x, u2 = gC.x;
        float uu = (gA.y + gB.y) + gC.y;

        // ===== regime 1: 3x3 adjugate chain =====
        float a00=Pp00+invs0, a01=Pp01, a02=Pp02;
        float a11=Pp11+invs1, a12=Pp12, a22=Pp22+invs2;
        float i00 = fmaf(a11,a22, -a12*a12);
        float i01 = fmaf(a02,a12, -a01*a22);
        float i02 = fmaf(a01,a12, -a02*a11);
        float det = fmaf(a00,i00, fmaf(a01,i01, a02*i02));
        float i11 = fmaf(a00,a22, -a02*a02);
        float i12 = fmaf(a01,a02, -a00*a12);
        float i22 = fmaf(a00,a11, -a01*a01);
        float idet = frcp(det);
        float rs1  = frsq(det);
        float ub0=u0*invs0, ub1=u1*invs1, ub2=u2*invs2;
        // packed {adj*ub, adj*pb} -> {aw_i, ah_i}
        f2 up0 = mk2(ub0, pb0), up1 = mk2(ub1, pb1), up2 = mk2(ub2, pb2);
        f2 wh0 = sp2(i02)*up2 + (sp2(i01)*up1 + sp2(i00)*up0);
        f2 wh1 = sp2(i12)*up2 + (sp2(i11)*up1 + sp2(i01)*up0);
        f2 wh2 = sp2(i22)*up2 + (sp2(i12)*up1 + sp2(i02)*up0);
        f2 spq = up2*wh2 + (up1*wh1 + up0*wh0);     // {ub.adj.ub, pb.adj.pb}
        float q1 = fmaf(spq.x, idet, t0 - fmaf(u2,ub2, fmaf(u1,ub1, u0*ub0)));
        float lik1 = fexp2(fmaf(-K2, q1, -C1f2)) * rs1;
        float w0=wh0.x*idet, w1=wh1.x*idet, w2=wh2.x*idet;
        float e1_0 = fmaf(-invs0, w0, ep0+ub0);
        float e1_1 = fmaf(-invs1, w1, ep1+ub1);
        float e1_2 = fmaf(-invs2, w2, ep2+ub2);
        float e1_3 = ep3 + fmaf(pb2,w2, fmaf(pb1,w1, pb0*w0));
        float pbh = spq.y;
        // off-chain epilogue precompute
        float ai00=k00*i00, ai01=k01*i01, ai02=k02*i02;
        float ai11=k11*i11, ai12=k12*i12, ai22=k22*i22;
        float b03=invs0*wh0.y, b13=invs1*wh1.y, b23=invs2*wh2.y;  // invs_i * ah_i

        // ===== regime 2: Sherman-Morrison =====
        float beta = Pp33;
        float denom = fmaf(beta, smm, 1.f);
        float iden  = frcp(denom);
        float rs2   = frsq(denom);
        float g2s = uu*iden;
        float q2  = fmaf(-beta*uu, g2s, t02);
        float lik2 = fexp2(fmaf(-K2, q2, -C2f2)) * rs2;
        float e2_0=fmaf(pb0,g2s,ep0), e2_1=fmaf(pb1,g2s,ep1);
        float e2_2=fmaf(pb2,g2s,ep2), e2_3=fmaf(Pp33,g2s,ep3);
        float k2s = smm*iden;

        // ===== IMM mixing (Delta form, adj-form P1) =====
        float num1 = lik1*pm;
        float num2 = lik2*w2f;
        float marg = num1+num2+1e-9f;
        acc2 -= flog2(marg);
        float imarg = frcp(marg);
        float pt1 = num1*imarg, pt2 = num2*imarg;
        float sig = pt1+pt2;
        float ptid = pt1*idet;
        float c3  = (pt1*pt2)*sig;
        float D0=e1_0-e2_0, D1=e1_1-e2_1, D2=e1_2-e2_2, D3=e1_3-e2_3;
        float cd0=c3*D0, cd1=c3*D1, cd2=c3*D2, cd3=c3*D3;
        float et0 = fmaf(pt1, D0, sig*e2_0);
        float et1 = fmaf(pt1, D1, sig*e2_1);
        float et2 = fmaf(pt1, D2, sig*e2_2);
        float et3 = fmaf(pt1, D3, sig*e2_3);
        float kap = pt2*k2s;
        float p3a0=kap*pb0, p3a1=kap*pb1, p3a2=kap*pb2, p3a3=kap*Pp33;

        float v;
        v = fmaf(pt1, invs0, pt2*Pp00); v = fmaf(-ai00, ptid, v);
        v = fmaf(-p3a0, pb0, v);        P00 = fmaf(cd0, D0, v);
        v = pt2*Pp01;                   v = fmaf(-ai01, ptid, v);
        v = fmaf(-p3a0, pb1, v);        P01 = fmaf(cd0, D1, v);
        v = pt2*Pp02;                   v = fmaf(-ai02, ptid, v);
        v = fmaf(-p3a0, pb2, v);        P02 = fmaf(cd0, D2, v);
        v = pt2*pb0;                    v = fmaf(b03, ptid, v);
        v = fmaf(-p3a0, Pp33, v);       P03 = fmaf(cd0, D3, v);
        v = fmaf(pt1, invs1, pt2*Pp11); v = fmaf(-ai11, ptid, v);
        v = fmaf(-p3a1, pb1, v);        P11 = fmaf(cd1, D1, v);
        v = pt2*Pp12;                   v = fmaf(-ai12, ptid, v);
        v = fmaf(-p3a1, pb2, v);        P12 = fmaf(cd1, D2, v);
        v = pt2*pb1;                    v = fmaf(b13, ptid, v);
        v = fmaf(-p3a1, Pp33, v);       P13 = fmaf(cd1, D3, v);
        v = fmaf(pt1, invs2, pt2*Pp22); v = fmaf(-ai22, ptid, v);
        v = fmaf(-p3a2, pb2, v);        P22 = fmaf(cd2, D2, v);
        v = pt2*pb2;                    v = fmaf(b23, ptid, v);
        v = fmaf(-p3a2, Pp33, v);       P23 = fmaf(cd2, D3, v);
        v = sig*Pp33;                   v = fmaf(-pbh, ptid, v);
        v = fmaf(-p3a3, Pp33, v);       P33 = fmaf(cd3, D3, v);

        prob1=pt1; prob2=pt2;
        eta0=et0; eta1v=et1; eta2v=et2; eta3=et3;
    }

    float acc = acc2 * LN2;
    #pragma unroll
    for (int off=32; off>0; off>>=1) acc += __shfl_down(acc, off);
    if (threadIdx.x==0) atomicAdd(out, acc);
}

extern "C" void kernel_launch(void* const* d_in, const int* in_sizes, int n_in,
                              void* d_out, int out_size, void* d_ws, size_t ws_size,
                              hipStream_t stream) {
    (void)in_sizes; (void)n_in; (void)d_ws; (void)ws_size;
    float* out = (float*)d_out;
    zero_kernel<<<1, 64, 0, stream>>>(out, out_size);
    rskf_kernel<<<NSER/64, 64, 0, stream>>>(
        (const float*)d_in[0], (const float*)d_in[1], (const float*)d_in[2],
        (const float*)d_in[3], (const float*)d_in[4], (const float*)d_in[5],
        (const float*)d_in[6], (const float*)d_in[7], (const float*)d_in[8],
        out);
}